// Round 3
// baseline (97.079 us; speedup 1.0000x reference)
//
#include <hip/hip_runtime.h>
#include <hip/hip_bf16.h>

typedef __bf16 bf16x8 __attribute__((ext_vector_type(8)));
typedef __bf16 bf16x4 __attribute__((ext_vector_type(4)));
typedef float  f32x4  __attribute__((ext_vector_type(4)));

#define NB  8
#define SEQ 2048
#define DM  1024
#define HD  64

__device__ __forceinline__ void gll16(const void* g, void* l) {
    __builtin_amdgcn_global_load_lds(
        (const __attribute__((address_space(1))) unsigned int*)g,
        (__attribute__((address_space(3))) unsigned int*)l, 16, 0, 0);
}

// ---------------- kernel 0: W (3 x [64,1024] f32) -> packed bf16 [192][1024]
__global__ void k_convw(const float* __restrict__ Wq, const float* __restrict__ Wk,
                        const float* __restrict__ Wv, __bf16* __restrict__ Wb) {
    int idx = blockIdx.x * blockDim.x + threadIdx.x;
    int e = idx * 4;
    const float* src;
    if (e < 65536)       src = Wq + e;
    else if (e < 131072) src = Wk + (e - 65536);
    else                 src = Wv + (e - 131072);
    float4 v = *reinterpret_cast<const float4*>(src);
    bf16x4 o;
    o[0] = (__bf16)v.x; o[1] = (__bf16)v.y; o[2] = (__bf16)v.z; o[3] = (__bf16)v.w;
    *reinterpret_cast<bf16x4*>(Wb + e) = o;
}

// ---------------- kernel 1: QKV projection, M=32/block, 512 thr (8 waves: 2M x 4N)
// X staged f32 via global_load_lds (double-buffered, XOR-swizzled source),
// W fragments straight from L2. Qb prescaled by 1/8.
__launch_bounds__(512)
__global__ void k_proj(const float* __restrict__ X, const __bf16* __restrict__ Wb,
                       __bf16* __restrict__ Qb, __bf16* __restrict__ Kb,
                       __bf16* __restrict__ Vt) {
    __shared__ __align__(16) float Xs[2][2048];   // 2 x 32 rows x 64 f32 (8 KB each)
    const int tid = threadIdx.x;
    const int w = tid >> 6, l = tid & 63;
    const int lr = l & 15, lg = l >> 4;
    const int wm = w >> 2, wn = w & 3;
    const int m0 = blockIdx.x * 32;

    // staging: wave w covers rows w*4 .. w*4+3 (16B units, source XOR-swizzled)
    const int srow = w * 4 + (l >> 4);
    const int sun  = (l & 15) ^ (srow & 15);
    const float* gsrc = X + (size_t)(m0 + srow) * DM + sun * 4;
    float* lbase = &Xs[0][0] + w * 256;           // lane's 16B lands at +l*16 (HW)

    // W fragment base pointers (L2-resident), col-tile n = wn*3+ct
    const __bf16* wp[3];
    #pragma unroll
    for (int ct = 0; ct < 3; ++ct)
        wp[ct] = Wb + (size_t)((wn * 3 + ct) * 16 + lr) * DM + lg * 8;

    f32x4 acc[3];
    #pragma unroll
    for (int ct = 0; ct < 3; ++ct) acc[ct] = f32x4{0.f, 0.f, 0.f, 0.f};

    const int rowA = wm * 16 + lr;
    // A-read LDS float indices (swizzle: unit u -> u ^ (rowA&15) = u ^ lr)
    int aidx[2][2];
    #pragma unroll
    for (int ks = 0; ks < 2; ++ks)
        #pragma unroll
        for (int h = 0; h < 2; ++h)
            aidx[ks][h] = rowA * 64 + ((ks * 8 + lg * 2 + h) ^ lr) * 4;

    gll16(gsrc, lbase);                            // stage kb=0 into buf 0
    __syncthreads();

    for (int kb16 = 0; kb16 < 16; ++kb16) {
        const int cur = kb16 & 1;
        if (kb16 < 15)
            gll16(gsrc + (kb16 + 1) * 64, lbase + (cur ^ 1) * 2048);
        const float* xb = &Xs[cur][0];
        #pragma unroll
        for (int ks = 0; ks < 2; ++ks) {
            f32x4 a0 = *reinterpret_cast<const f32x4*>(xb + aidx[ks][0]);
            f32x4 a1 = *reinterpret_cast<const f32x4*>(xb + aidx[ks][1]);
            bf16x8 af;
            #pragma unroll
            for (int j = 0; j < 4; ++j) { af[j] = (__bf16)a0[j]; af[4 + j] = (__bf16)a1[j]; }
            #pragma unroll
            for (int ct = 0; ct < 3; ++ct) {
                bf16x8 bf = *reinterpret_cast<const bf16x8*>(wp[ct] + kb16 * 64 + ks * 32);
                acc[ct] = __builtin_amdgcn_mfma_f32_16x16x32_bf16(af, bf, acc[ct], 0, 0, 0);
            }
        }
        __syncthreads();   // drains the prefetch (vmcnt 0) + protects buffers
    }

    const int rowbase = m0 + wm * 16 + lg * 4;
    #pragma unroll
    for (int ct = 0; ct < 3; ++ct) {
        const int n = wn * 3 + ct;
        const int mtx = n >> 2;
        const int d = (n & 3) * 16 + lr;
        if (mtx == 0) {
            #pragma unroll
            for (int r = 0; r < 4; ++r)
                Qb[(size_t)(rowbase + r) * HD + d] = (__bf16)(acc[ct][r] * 0.125f);
        } else if (mtx == 1) {
            #pragma unroll
            for (int r = 0; r < 4; ++r)
                Kb[(size_t)(rowbase + r) * HD + d] = (__bf16)acc[ct][r];
        } else {
            int bb = rowbase >> 11;
            int s0 = rowbase & 2047;
            bf16x4 vv;
            #pragma unroll
            for (int r = 0; r < 4; ++r) vv[r] = (__bf16)acc[ct][r];
            *reinterpret_cast<bf16x4*>(Vt + ((size_t)bb * HD + d) * SEQ + s0) = vv;
        }
    }
}

// ---------------- kernel 2: chunked causal flash attention (split-K) with
// register-prefetched K/V tiles (async-STAGE split).
__launch_bounds__(256)
__global__ void k_attn(const __bf16* __restrict__ Qb, const __bf16* __restrict__ Kb,
                       const __bf16* __restrict__ Vt, __bf16* __restrict__ Opart,
                       float* __restrict__ ML, int T, int NC) {
    const int bid = blockIdx.x;
    const int b = bid / (32 * NC);
    const int rem = bid - b * 32 * NC;
    const int qt = rem / NC;
    const int c = rem - qt * NC;
    if (c * T > qt) return;
    const int kt0 = c * T;
    const int nt = min(T, qt + 1 - kt0);
    const int q0 = qt * 64;

    __shared__ __align__(16) __bf16 Ks[64][72];
    __shared__ __align__(16) __bf16 Vs[64][72];   // [d][key]
    __shared__ __align__(16) __bf16 Ps[64][72];
    const int tid = threadIdx.x;
    const int w = tid >> 6, l = tid & 63;
    const int lr = l & 15, lg = l >> 4;
    const __bf16* Qp = Qb + (size_t)b * SEQ * HD;
    const __bf16* Kp = Kb + (size_t)b * SEQ * HD;
    const __bf16* Vp = Vt + (size_t)b * HD * SEQ;

    const int srow = tid >> 3, sc8 = (tid & 7) * 8;   // staging coords (2 chunks)

    // Q fragments to registers (reused whole chunk)
    bf16x8 qa[2];
    #pragma unroll
    for (int ks = 0; ks < 2; ++ks)
        qa[ks] = *reinterpret_cast<const bf16x8*>(
            Qp + (size_t)(q0 + 16 * w + lr) * HD + ks * 32 + lg * 8);

    // prefetch tile kt0 into regs
    bf16x8 kpre[2], vpre[2];
    {
        const int k0 = kt0 * 64;
        #pragma unroll
        for (int i = 0; i < 2; ++i) {
            int row = srow + 32 * i;
            kpre[i] = *reinterpret_cast<const bf16x8*>(Kp + (size_t)(k0 + row) * HD + sc8);
            vpre[i] = *reinterpret_cast<const bf16x8*>(Vp + (size_t)row * SEQ + k0 + sc8);
        }
    }

    f32x4 oacc[4];
    float mrow[4], lrow[4];
    #pragma unroll
    for (int r = 0; r < 4; ++r) {
        oacc[r] = f32x4{0.f, 0.f, 0.f, 0.f};
        mrow[r] = -1e30f;
        lrow[r] = 0.f;
    }

    for (int it = 0; it < nt; ++it) {
        const int kt = kt0 + it;
        __syncthreads();   // previous iteration done reading LDS
        #pragma unroll
        for (int i = 0; i < 2; ++i) {
            int row = srow + 32 * i;
            *reinterpret_cast<bf16x8*>(&Ks[row][sc8]) = kpre[i];
            *reinterpret_cast<bf16x8*>(&Vs[row][sc8]) = vpre[i];
        }
        __syncthreads();
        if (it + 1 < nt) {   // issue next tile's loads; land under compute
            const int k0n = (kt + 1) * 64;
            #pragma unroll
            for (int i = 0; i < 2; ++i) {
                int row = srow + 32 * i;
                kpre[i] = *reinterpret_cast<const bf16x8*>(Kp + (size_t)(k0n + row) * HD + sc8);
                vpre[i] = *reinterpret_cast<const bf16x8*>(Vp + (size_t)row * SEQ + k0n + sc8);
            }
        }

        f32x4 sacc[4];
        #pragma unroll
        for (int t = 0; t < 4; ++t) sacc[t] = f32x4{0.f, 0.f, 0.f, 0.f};
        #pragma unroll
        for (int ks = 0; ks < 2; ++ks) {
            #pragma unroll
            for (int t = 0; t < 4; ++t) {
                bf16x8 bb = *reinterpret_cast<const bf16x8*>(&Ks[16 * t + lr][ks * 32 + lg * 8]);
                sacc[t] = __builtin_amdgcn_mfma_f32_16x16x32_bf16(qa[ks], bb, sacc[t], 0, 0, 0);
            }
        }

        const bool diag = (kt == qt);
        #pragma unroll
        for (int r = 0; r < 4; ++r) {
            float mx = -1e30f;
            #pragma unroll
            for (int t = 0; t < 4; ++t) {
                float v = sacc[t][r];
                if (diag && (16 * t + lr) > (16 * w + lg * 4 + r)) v = -1e30f;
                sacc[t][r] = v;
                mx = fmaxf(mx, v);
            }
            mx = fmaxf(mx, __shfl_xor(mx, 1));
            mx = fmaxf(mx, __shfl_xor(mx, 2));
            mx = fmaxf(mx, __shfl_xor(mx, 4));
            mx = fmaxf(mx, __shfl_xor(mx, 8));
            float mnew = fmaxf(mrow[r], mx);
            float fsc = __expf(mrow[r] - mnew);
            mrow[r] = mnew;
            float rs = 0.f;
            #pragma unroll
            for (int t = 0; t < 4; ++t) {
                float p = __expf(sacc[t][r] - mnew);
                sacc[t][r] = p;
                rs += p;
            }
            rs += __shfl_xor(rs, 1);
            rs += __shfl_xor(rs, 2);
            rs += __shfl_xor(rs, 4);
            rs += __shfl_xor(rs, 8);
            lrow[r] = lrow[r] * fsc + rs;
            #pragma unroll
            for (int t = 0; t < 4; ++t) oacc[t][r] *= fsc;
        }

        #pragma unroll
        for (int t = 0; t < 4; ++t)
            #pragma unroll
            for (int r = 0; r < 4; ++r)
                Ps[16 * w + lg * 4 + r][16 * t + lr] = (__bf16)sacc[t][r];

        #pragma unroll
        for (int ks = 0; ks < 2; ++ks) {
            bf16x8 pa = *reinterpret_cast<const bf16x8*>(&Ps[16 * w + lr][ks * 32 + lg * 8]);
            #pragma unroll
            for (int t2 = 0; t2 < 4; ++t2) {
                bf16x8 vb = *reinterpret_cast<const bf16x8*>(&Vs[16 * t2 + lr][ks * 32 + lg * 8]);
                oacc[t2] = __builtin_amdgcn_mfma_f32_16x16x32_bf16(pa, vb, oacc[t2], 0, 0, 0);
            }
        }
    }

    const size_t slot = (size_t)bid;
    __bf16* op = Opart + slot * 4096;
    #pragma unroll
    for (int t2 = 0; t2 < 4; ++t2)
        #pragma unroll
        for (int r = 0; r < 4; ++r)
            op[(16 * w + lg * 4 + r) * 64 + 16 * t2 + lr] = (__bf16)oacc[t2][r];
    if (lr == 0) {
        float* ml = ML + slot * 128;
        #pragma unroll
        for (int r = 0; r < 4; ++r) {
            int row = 16 * w + lg * 4 + r;
            ml[row * 2]     = mrow[r];
            ml[row * 2 + 1] = lrow[r];
        }
    }
}

// ---------------- kernel 3: merge partial chunks -> Out [B][S][64] f32
__launch_bounds__(256)
__global__ void k_merge(const __bf16* __restrict__ Opart, const float* __restrict__ ML,
                        float* __restrict__ Out, int T, int NC) {
    const int bq = blockIdx.x;
    const int qt = bq & 31;
    const int nc = qt / T + 1;
    const int row = threadIdx.x >> 2;
    const int cg = (threadIdx.x & 3) * 16;
    const int base = bq * NC;

    float M = -1e30f;
    for (int c = 0; c < nc; ++c)
        M = fmaxf(M, ML[(size_t)(base + c) * 128 + row * 2]);

    float L = 0.f;
    f32x4 a0{0,0,0,0}, a1{0,0,0,0}, a2{0,0,0,0}, a3{0,0,0,0};
    for (int c = 0; c < nc; ++c) {
        const float* ml = ML + (size_t)(base + c) * 128 + row * 2;
        float wgt = __expf(ml[0] - M);
        L += ml[1] * wgt;
        const __bf16* op = Opart + (size_t)(base + c) * 4096 + row * 64 + cg;
        bf16x8 v0 = *reinterpret_cast<const bf16x8*>(op);
        bf16x8 v1 = *reinterpret_cast<const bf16x8*>(op + 8);
        #pragma unroll
        for (int j = 0; j < 4; ++j) {
            a0[j] += wgt * (float)v0[j];
            a1[j] += wgt * (float)v0[4 + j];
            a2[j] += wgt * (float)v1[j];
            a3[j] += wgt * (float)v1[4 + j];
        }
    }
    float inv = 1.f / L;
    #pragma unroll
    for (int j = 0; j < 4; ++j) { a0[j] *= inv; a1[j] *= inv; a2[j] *= inv; a3[j] *= inv; }
    float* o = Out + ((size_t)bq * 64 + row) * 64 + cg;
    *reinterpret_cast<f32x4*>(o)      = a0;
    *reinterpret_cast<f32x4*>(o + 4)  = a1;
    *reinterpret_cast<f32x4*>(o + 8)  = a2;
    *reinterpret_cast<f32x4*>(o + 12) = a3;
}

extern "C" void kernel_launch(void* const* d_in, const int* in_sizes, int n_in,
                              void* d_out, int out_size, void* d_ws, size_t ws_size,
                              hipStream_t stream) {
    const float* x  = (const float*)d_in[0];
    const float* wq = (const float*)d_in[1];
    const float* wk = (const float*)d_in[2];
    const float* wv = (const float*)d_in[3];
    char* ws = (char*)d_ws;
    __bf16* Wb = (__bf16*)ws;
    __bf16* Qb = (__bf16*)(ws + 524288);
    __bf16* Kb = (__bf16*)(ws + 524288 + 2097152);
    __bf16* Vt = (__bf16*)(ws + 524288 + 2 * 2097152);
    const size_t base = 524288 + 3 * 2097152;
    float* out = (float*)d_out;

    int T;
    if (ws_size >= base + (size_t)2048 * 8704)      T = 4;
    else if (ws_size >= base + (size_t)1024 * 8704) T = 8;
    else                                            T = 32;
    const int NC = 32 / T;
    const int slots = 8 * 32 * NC;
    float*  ML    = (float*)(ws + base);
    __bf16* Opart = (__bf16*)(ws + base + (size_t)slots * 512);

    hipLaunchKernelGGL(k_convw, dim3(192), dim3(256), 0, stream, wq, wk, wv, Wb);
    hipLaunchKernelGGL(k_proj,  dim3(512), dim3(512), 0, stream, x, Wb, Qb, Kb, Vt);
    hipLaunchKernelGGL(k_attn,  dim3(8 * 32 * NC), dim3(256), 0, stream,
                       Qb, Kb, Vt, Opart, ML, T, NC);
    hipLaunchKernelGGL(k_merge, dim3(256), dim3(256), 0, stream, Opart, ML, out, T, NC);
}

// Round 4
// 60.758 us; speedup vs baseline: 1.5978x; 1.5978x over previous
//
#include <hip/hip_runtime.h>
#include <hip/hip_bf16.h>

typedef __bf16 bf16x8 __attribute__((ext_vector_type(8)));
typedef __bf16 bf16x4 __attribute__((ext_vector_type(4)));
typedef float  f32x4  __attribute__((ext_vector_type(4)));

#define NB  8
#define SEQ 2048
#define DM  1024
#define HD  64

#define WAITV5 asm volatile("s_waitcnt vmcnt(5)" ::: "memory")
#define WAITV0 asm volatile("s_waitcnt vmcnt(0)" ::: "memory")

__device__ __forceinline__ void gll16(const void* g, void* l) {
    __builtin_amdgcn_global_load_lds(
        (const __attribute__((address_space(1))) unsigned int*)g,
        (__attribute__((address_space(3))) unsigned int*)l, 16, 0, 0);
}

// ---------------- kernel 0: W (3 x [64,1024] f32) -> packed bf16 [192][1024]
__global__ void k_convw(const float* __restrict__ Wq, const float* __restrict__ Wk,
                        const float* __restrict__ Wv, __bf16* __restrict__ Wb) {
    int idx = blockIdx.x * blockDim.x + threadIdx.x;
    int e = idx * 4;
    const float* src;
    if (e < 65536)       src = Wq + e;
    else if (e < 131072) src = Wk + (e - 65536);
    else                 src = Wv + (e - 131072);
    float4 v = *reinterpret_cast<const float4*>(src);
    bf16x4 o;
    o[0] = (__bf16)v.x; o[1] = (__bf16)v.y; o[2] = (__bf16)v.z; o[3] = (__bf16)v.w;
    *reinterpret_cast<bf16x4*>(Wb + e) = o;
}

// ---------------- kernel 1: QKV projection with counted-vmcnt ring-3 pipeline.
// Block: 512 thr (8 waves = 2 Mgroups x 4 Ngroups), M=64 rows, grid 256 (1/CU).
// Each k-tile (K=64): X 16KB f32 + W 24KB bf16 staged via global_load_lds into
// a 3-deep LDS ring; waits are s_waitcnt vmcnt(5) (tile t done, t+1/t+2 in
// flight across barriers). ALL global reads go through the ring -> no
// compiler vmem loads pollute the vmcnt stream. XOR-swizzled sources.
__launch_bounds__(512)
__global__ void k_proj(const float* __restrict__ X, const __bf16* __restrict__ Wb,
                       __bf16* __restrict__ Qb, __bf16* __restrict__ Kb,
                       __bf16* __restrict__ Vt) {
    __shared__ __align__(16) float  Xs[3][4096];    // 3 x 16KB
    __shared__ __align__(16) __bf16 Ws[3][12288];   // 3 x 24KB
    const int tid = threadIdx.x;
    const int w = tid >> 6, l = tid & 63;
    const int lr = l & 15, lg = l >> 4;
    const int wm = w >> 2, wn = w & 3;
    const int m0 = blockIdx.x * 64;

    // staging sources (pre-swizzled): X 2 units/thread, W 3 units/thread
    const float* xsrc[2];
    #pragma unroll
    for (int j = 0; j < 2; ++j) {
        int ux = w * 128 + j * 64 + l;
        int r_ = ux >> 4, c_ = ux & 15;
        xsrc[j] = X + (size_t)(m0 + r_) * DM + (c_ ^ (r_ & 15)) * 4;
    }
    const __bf16* wsrc[3];
    #pragma unroll
    for (int j = 0; j < 3; ++j) {
        int uw = w * 192 + j * 64 + l;
        int r_ = uw >> 3, c_ = uw & 7;
        wsrc[j] = Wb + (size_t)r_ * DM + (c_ ^ (r_ & 7)) * 8;
    }

    f32x4 acc[2][3];
    #pragma unroll
    for (int mt = 0; mt < 2; ++mt)
        #pragma unroll
        for (int ct = 0; ct < 3; ++ct)
            acc[mt][ct] = f32x4{0.f, 0.f, 0.f, 0.f};

    // LDS read bases
    int abase[2], bbase[3];
    #pragma unroll
    for (int mt = 0; mt < 2; ++mt) abase[mt] = (wm * 32 + mt * 16 + lr) * 64;
    #pragma unroll
    for (int ct = 0; ct < 3; ++ct) bbase[ct] = ((wn * 3 + ct) * 16 + lr) * 64;

    // prologue: stage tiles 0,1
    #pragma unroll
    for (int t = 0; t < 2; ++t) {
        #pragma unroll
        for (int j = 0; j < 2; ++j) gll16(xsrc[j] + t * 64, &Xs[t][w * 512 + j * 256]);
        #pragma unroll
        for (int j = 0; j < 3; ++j) gll16(wsrc[j] + t * 64, &Ws[t][w * 1536 + j * 512]);
    }

    int sl = 0;
    for (int t = 0; t < 16; ++t) {
        if (t < 15) WAITV5; else WAITV0;
        __builtin_amdgcn_s_barrier();
        if (t + 2 < 16) {
            int si = sl + 2; if (si >= 3) si -= 3;
            #pragma unroll
            for (int j = 0; j < 2; ++j)
                gll16(xsrc[j] + (t + 2) * 64, &Xs[si][w * 512 + j * 256]);
            #pragma unroll
            for (int j = 0; j < 3; ++j)
                gll16(wsrc[j] + (t + 2) * 64, &Ws[si][w * 1536 + j * 512]);
        }
        const float*  Xp = &Xs[sl][0];
        const __bf16* Wp = &Ws[sl][0];
        #pragma unroll
        for (int ks = 0; ks < 2; ++ks) {
            bf16x8 af[2];
            #pragma unroll
            for (int mt = 0; mt < 2; ++mt) {
                f32x4 a0 = *reinterpret_cast<const f32x4*>(Xp + abase[mt] + ((ks * 8 + lg * 2)     ^ lr) * 4);
                f32x4 a1 = *reinterpret_cast<const f32x4*>(Xp + abase[mt] + ((ks * 8 + lg * 2 + 1) ^ lr) * 4);
                #pragma unroll
                for (int j = 0; j < 4; ++j) { af[mt][j] = (__bf16)a0[j]; af[mt][4 + j] = (__bf16)a1[j]; }
            }
            #pragma unroll
            for (int ct = 0; ct < 3; ++ct) {
                bf16x8 bf = *reinterpret_cast<const bf16x8*>(
                    Wp + bbase[ct] + (((ks * 4 + lg) ^ (lr & 7)) * 8));
                #pragma unroll
                for (int mt = 0; mt < 2; ++mt)
                    acc[mt][ct] = __builtin_amdgcn_mfma_f32_16x16x32_bf16(af[mt], bf, acc[mt][ct], 0, 0, 0);
            }
        }
        ++sl; if (sl >= 3) sl = 0;
    }

    #pragma unroll
    for (int mt = 0; mt < 2; ++mt) {
        const int rowbase = m0 + wm * 32 + mt * 16 + lg * 4;
        #pragma unroll
        for (int ct = 0; ct < 3; ++ct) {
            const int ntile = wn * 3 + ct;
            const int mtx = ntile >> 2;
            const int d = (ntile & 3) * 16 + lr;
            if (mtx == 0) {
                #pragma unroll
                for (int r = 0; r < 4; ++r)
                    Qb[(size_t)(rowbase + r) * HD + d] = (__bf16)(acc[mt][ct][r] * 0.125f);
            } else if (mtx == 1) {
                #pragma unroll
                for (int r = 0; r < 4; ++r)
                    Kb[(size_t)(rowbase + r) * HD + d] = (__bf16)acc[mt][ct][r];
            } else {
                int bb = rowbase >> 11;
                int s0 = rowbase & 2047;
                bf16x4 vv;
                #pragma unroll
                for (int r = 0; r < 4; ++r) vv[r] = (__bf16)acc[mt][ct][r];
                *reinterpret_cast<bf16x4*>(Vt + ((size_t)bb * HD + d) * SEQ + s0) = vv;
            }
        }
    }
}

// ---------------- kernel 2: chunked causal flash attention (split-K),
// swapped QK^T: lane holds P[16 keys][query=lr] -> in-lane softmax + 2 shfl.
__launch_bounds__(256)
__global__ void k_attn(const __bf16* __restrict__ Qb, const __bf16* __restrict__ Kb,
                       const __bf16* __restrict__ Vt, __bf16* __restrict__ Opart,
                       float* __restrict__ ML, int T, int NC) {
    const int bid = blockIdx.x;
    const int b = bid / (32 * NC);
    const int rem = bid - b * 32 * NC;
    const int qt = rem / NC;
    const int c = rem - qt * NC;
    if (c * T > qt) return;
    const int kt0 = c * T;
    const int nt = min(T, qt + 1 - kt0);
    const int q0 = qt * 64;

    __shared__ __align__(16) __bf16 Ks[64][72];
    __shared__ __align__(16) __bf16 Vs[64][72];   // [d][key]
    __shared__ __align__(16) __bf16 Ps[64][72];
    const int tid = threadIdx.x;
    const int w = tid >> 6, l = tid & 63;
    const int lr = l & 15, lg = l >> 4;
    const __bf16* Qp = Qb + (size_t)b * SEQ * HD;
    const __bf16* Kp = Kb + (size_t)b * SEQ * HD;
    const __bf16* Vp = Vt + (size_t)b * HD * SEQ;

    const int srow = tid >> 3, sc8 = (tid & 7) * 8;
    const int myq = q0 + 16 * w + lr;    // query this lane softmaxes

    bf16x8 qa[2];
    #pragma unroll
    for (int ks = 0; ks < 2; ++ks)
        qa[ks] = *reinterpret_cast<const bf16x8*>(
            Qp + (size_t)(q0 + 16 * w + lr) * HD + ks * 32 + lg * 8);

    bf16x8 kpre[2], vpre[2];
    {
        const int k0 = kt0 * 64;
        #pragma unroll
        for (int i = 0; i < 2; ++i) {
            int row = srow + 32 * i;
            kpre[i] = *reinterpret_cast<const bf16x8*>(Kp + (size_t)(k0 + row) * HD + sc8);
            vpre[i] = *reinterpret_cast<const bf16x8*>(Vp + (size_t)row * SEQ + k0 + sc8);
        }
    }

    f32x4 oacc[4];
    #pragma unroll
    for (int r = 0; r < 4; ++r) oacc[r] = f32x4{0.f, 0.f, 0.f, 0.f};
    float m = -1e30f, lsum = 0.f;

    for (int it = 0; it < nt; ++it) {
        const int kt = kt0 + it;
        const int k0 = kt * 64;
        __syncthreads();
        #pragma unroll
        for (int i = 0; i < 2; ++i) {
            int row = srow + 32 * i;
            *reinterpret_cast<bf16x8*>(&Ks[row][sc8]) = kpre[i];
            *reinterpret_cast<bf16x8*>(&Vs[row][sc8]) = vpre[i];
        }
        __syncthreads();
        if (it + 1 < nt) {
            const int k0n = (kt + 1) * 64;
            #pragma unroll
            for (int i = 0; i < 2; ++i) {
                int row = srow + 32 * i;
                kpre[i] = *reinterpret_cast<const bf16x8*>(Kp + (size_t)(k0n + row) * HD + sc8);
                vpre[i] = *reinterpret_cast<const bf16x8*>(Vp + (size_t)row * SEQ + k0n + sc8);
            }
        }

        // S^T: sacc[t][r] = S[key = k0+16t+lg*4+r][query = myq]
        f32x4 sacc[4];
        #pragma unroll
        for (int t = 0; t < 4; ++t) sacc[t] = f32x4{0.f, 0.f, 0.f, 0.f};
        #pragma unroll
        for (int ks = 0; ks < 2; ++ks) {
            #pragma unroll
            for (int t = 0; t < 4; ++t) {
                bf16x8 kf = *reinterpret_cast<const bf16x8*>(&Ks[16 * t + lr][ks * 32 + lg * 8]);
                sacc[t] = __builtin_amdgcn_mfma_f32_16x16x32_bf16(kf, qa[ks], sacc[t], 0, 0, 0);
            }
        }

        const bool diag = (kt == qt);
        float pmax = -1e30f;
        #pragma unroll
        for (int t = 0; t < 4; ++t)
            #pragma unroll
            for (int r = 0; r < 4; ++r) {
                float v = sacc[t][r];
                if (diag && (k0 + 16 * t + lg * 4 + r) > myq) v = -1e30f;
                sacc[t][r] = v;
                pmax = fmaxf(pmax, v);
            }
        pmax = fmaxf(pmax, __shfl_xor(pmax, 16));
        pmax = fmaxf(pmax, __shfl_xor(pmax, 32));
        float mnew = fmaxf(m, pmax);
        float fsc = __expf(m - mnew);
        m = mnew;
        float rs = 0.f;
        #pragma unroll
        for (int t = 0; t < 4; ++t)
            #pragma unroll
            for (int r = 0; r < 4; ++r) {
                float p = __expf(sacc[t][r] - mnew);
                sacc[t][r] = p;
                rs += p;
            }
        rs += __shfl_xor(rs, 16);
        rs += __shfl_xor(rs, 32);
        lsum = lsum * fsc + rs;

        // rescale O: need fsc of query lg*4+r (lives at lane (l&48)|(lg*4+r))
        #pragma unroll
        for (int r = 0; r < 4; ++r) {
            float fq = __shfl(fsc, (l & 48) + lg * 4 + r);
            #pragma unroll
            for (int t2 = 0; t2 < 4; ++t2) oacc[t2][r] *= fq;
        }

        // P -> LDS, packed b64 (wave-private rows)
        #pragma unroll
        for (int t = 0; t < 4; ++t) {
            bf16x4 pv;
            #pragma unroll
            for (int r = 0; r < 4; ++r) pv[r] = (__bf16)sacc[t][r];
            *reinterpret_cast<bf16x4*>(&Ps[16 * w + lr][16 * t + lg * 4]) = pv;
        }

        // O += P V
        #pragma unroll
        for (int ks = 0; ks < 2; ++ks) {
            bf16x8 pa = *reinterpret_cast<const bf16x8*>(&Ps[16 * w + lr][ks * 32 + lg * 8]);
            #pragma unroll
            for (int t2 = 0; t2 < 4; ++t2) {
                bf16x8 vb = *reinterpret_cast<const bf16x8*>(&Vs[16 * t2 + lr][ks * 32 + lg * 8]);
                oacc[t2] = __builtin_amdgcn_mfma_f32_16x16x32_bf16(pa, vb, oacc[t2], 0, 0, 0);
            }
        }
    }

    const size_t slot = (size_t)bid;
    __bf16* op = Opart + slot * 4096;
    #pragma unroll
    for (int t2 = 0; t2 < 4; ++t2)
        #pragma unroll
        for (int r = 0; r < 4; ++r)
            op[(16 * w + lg * 4 + r) * 64 + 16 * t2 + lr] = (__bf16)oacc[t2][r];
    if (lg == 0) {
        float* ml = ML + slot * 128;
        int row = 16 * w + lr;
        ml[row * 2]     = m;
        ml[row * 2 + 1] = lsum;
    }
}

// ---------------- kernel 3: merge partial chunks -> Out [B][S][64] f32
__launch_bounds__(256)
__global__ void k_merge(const __bf16* __restrict__ Opart, const float* __restrict__ ML,
                        float* __restrict__ Out, int T, int NC) {
    const int bq = blockIdx.x;
    const int qt = bq & 31;
    const int nc = qt / T + 1;
    const int row = threadIdx.x >> 2;
    const int cg = (threadIdx.x & 3) * 16;
    const int base = bq * NC;

    float M = -1e30f;
    for (int c = 0; c < nc; ++c)
        M = fmaxf(M, ML[(size_t)(base + c) * 128 + row * 2]);

    float L = 0.f;
    f32x4 a0{0,0,0,0}, a1{0,0,0,0}, a2{0,0,0,0}, a3{0,0,0,0};
    for (int c = 0; c < nc; ++c) {
        const float* ml = ML + (size_t)(base + c) * 128 + row * 2;
        float wgt = __expf(ml[0] - M);
        L += ml[1] * wgt;
        const __bf16* op = Opart + (size_t)(base + c) * 4096 + row * 64 + cg;
        bf16x8 v0 = *reinterpret_cast<const bf16x8*>(op);
        bf16x8 v1 = *reinterpret_cast<const bf16x8*>(op + 8);
        #pragma unroll
        for (int j = 0; j < 4; ++j) {
            a0[j] += wgt * (float)v0[j];
            a1[j] += wgt * (float)v0[4 + j];
            a2[j] += wgt * (float)v1[j];
            a3[j] += wgt * (float)v1[4 + j];
        }
    }
    float inv = 1.f / L;
    #pragma unroll
    for (int j = 0; j < 4; ++j) { a0[j] *= inv; a1[j] *= inv; a2[j] *= inv; a3[j] *= inv; }
    float* o = Out + ((size_t)bq * 64 + row) * 64 + cg;
    *reinterpret_cast<f32x4*>(o)      = a0;
    *reinterpret_cast<f32x4*>(o + 4)  = a1;
    *reinterpret_cast<f32x4*>(o + 8)  = a2;
    *reinterpret_cast<f32x4*>(o + 12) = a3;
}

extern "C" void kernel_launch(void* const* d_in, const int* in_sizes, int n_in,
                              void* d_out, int out_size, void* d_ws, size_t ws_size,
                              hipStream_t stream) {
    const float* x  = (const float*)d_in[0];
    const float* wq = (const float*)d_in[1];
    const float* wk = (const float*)d_in[2];
    const float* wv = (const float*)d_in[3];
    char* ws = (char*)d_ws;
    __bf16* Wb = (__bf16*)ws;
    __bf16* Qb = (__bf16*)(ws + 524288);
    __bf16* Kb = (__bf16*)(ws + 524288 + 2097152);
    __bf16* Vt = (__bf16*)(ws + 524288 + 2 * 2097152);
    const size_t base = 524288 + 3 * 2097152;
    float* out = (float*)d_out;

    int T;
    if (ws_size >= base + (size_t)2048 * 8704)      T = 4;
    else if (ws_size >= base + (size_t)1024 * 8704) T = 8;
    else                                            T = 32;
    const int NC = 32 / T;
    const int slots = 8 * 32 * NC;
    float*  ML    = (float*)(ws + base);
    __bf16* Opart = (__bf16*)(ws + base + (size_t)slots * 512);

    hipLaunchKernelGGL(k_convw, dim3(192), dim3(256), 0, stream, wq, wk, wv, Wb);
    hipLaunchKernelGGL(k_proj,  dim3(256), dim3(512), 0, stream, x, Wb, Qb, Kb, Vt);
    hipLaunchKernelGGL(k_attn,  dim3(8 * 32 * NC), dim3(256), 0, stream,
                       Qb, Kb, Vt, Opart, ML, T, NC);
    hipLaunchKernelGGL(k_merge, dim3(256), dim3(256), 0, stream, Opart, ML, out, T, NC);
}

// Round 5
// 59.764 us; speedup vs baseline: 1.6244x; 1.0166x over previous
//
#include <hip/hip_runtime.h>
#include <hip/hip_bf16.h>

typedef __bf16 bf16x8 __attribute__((ext_vector_type(8)));
typedef __bf16 bf16x4 __attribute__((ext_vector_type(4)));
typedef float  f32x4  __attribute__((ext_vector_type(4)));

#define NB  8
#define SEQ 2048
#define DM  1024
#define HD  64

#define WAITV5 asm volatile("s_waitcnt vmcnt(5)" ::: "memory")
#define WAITV0 asm volatile("s_waitcnt vmcnt(0)" ::: "memory")

__device__ __forceinline__ void gll16(const void* g, void* l) {
    __builtin_amdgcn_global_load_lds(
        (const __attribute__((address_space(1))) unsigned int*)g,
        (__attribute__((address_space(3))) unsigned int*)l, 16, 0, 0);
}

// ---------------- kernel 0: W (3 x [64,1024] f32) -> packed bf16 [192][1024]
__global__ void k_convw(const float* __restrict__ Wq, const float* __restrict__ Wk,
                        const float* __restrict__ Wv, __bf16* __restrict__ Wb) {
    int idx = blockIdx.x * blockDim.x + threadIdx.x;
    int e = idx * 4;
    const float* src;
    if (e < 65536)       src = Wq + e;
    else if (e < 131072) src = Wk + (e - 65536);
    else                 src = Wv + (e - 131072);
    float4 v = *reinterpret_cast<const float4*>(src);
    bf16x4 o;
    o[0] = (__bf16)v.x; o[1] = (__bf16)v.y; o[2] = (__bf16)v.z; o[3] = (__bf16)v.w;
    *reinterpret_cast<bf16x4*>(Wb + e) = o;
}

// ---------------- kernel 1: QKV projection, counted-vmcnt ring-3 (unchanged)
// Qb prescaled by 0.125 * log2(e) so attention scores are in log2 domain.
__launch_bounds__(512)
__global__ void k_proj(const float* __restrict__ X, const __bf16* __restrict__ Wb,
                       __bf16* __restrict__ Qb, __bf16* __restrict__ Kb,
                       __bf16* __restrict__ Vt) {
    __shared__ __align__(16) float  Xs[3][4096];
    __shared__ __align__(16) __bf16 Ws[3][12288];
    const int tid = threadIdx.x;
    const int w = tid >> 6, l = tid & 63;
    const int lr = l & 15, lg = l >> 4;
    const int wm = w >> 2, wn = w & 3;
    const int m0 = blockIdx.x * 64;

    const float* xsrc[2];
    #pragma unroll
    for (int j = 0; j < 2; ++j) {
        int ux = w * 128 + j * 64 + l;
        int r_ = ux >> 4, c_ = ux & 15;
        xsrc[j] = X + (size_t)(m0 + r_) * DM + (c_ ^ (r_ & 15)) * 4;
    }
    const __bf16* wsrc[3];
    #pragma unroll
    for (int j = 0; j < 3; ++j) {
        int uw = w * 192 + j * 64 + l;
        int r_ = uw >> 3, c_ = uw & 7;
        wsrc[j] = Wb + (size_t)r_ * DM + (c_ ^ (r_ & 7)) * 8;
    }

    f32x4 acc[2][3];
    #pragma unroll
    for (int mt = 0; mt < 2; ++mt)
        #pragma unroll
        for (int ct = 0; ct < 3; ++ct)
            acc[mt][ct] = f32x4{0.f, 0.f, 0.f, 0.f};

    int abase[2], bbase[3];
    #pragma unroll
    for (int mt = 0; mt < 2; ++mt) abase[mt] = (wm * 32 + mt * 16 + lr) * 64;
    #pragma unroll
    for (int ct = 0; ct < 3; ++ct) bbase[ct] = ((wn * 3 + ct) * 16 + lr) * 64;

    #pragma unroll
    for (int t = 0; t < 2; ++t) {
        #pragma unroll
        for (int j = 0; j < 2; ++j) gll16(xsrc[j] + t * 64, &Xs[t][w * 512 + j * 256]);
        #pragma unroll
        for (int j = 0; j < 3; ++j) gll16(wsrc[j] + t * 64, &Ws[t][w * 1536 + j * 512]);
    }

    int sl = 0;
    for (int t = 0; t < 16; ++t) {
        if (t < 15) WAITV5; else WAITV0;
        __builtin_amdgcn_s_barrier();
        if (t + 2 < 16) {
            int si = sl + 2; if (si >= 3) si -= 3;
            #pragma unroll
            for (int j = 0; j < 2; ++j)
                gll16(xsrc[j] + (t + 2) * 64, &Xs[si][w * 512 + j * 256]);
            #pragma unroll
            for (int j = 0; j < 3; ++j)
                gll16(wsrc[j] + (t + 2) * 64, &Ws[si][w * 1536 + j * 512]);
        }
        const float*  Xp = &Xs[sl][0];
        const __bf16* Wp = &Ws[sl][0];
        #pragma unroll
        for (int ks = 0; ks < 2; ++ks) {
            bf16x8 af[2];
            #pragma unroll
            for (int mt = 0; mt < 2; ++mt) {
                f32x4 a0 = *reinterpret_cast<const f32x4*>(Xp + abase[mt] + ((ks * 8 + lg * 2)     ^ lr) * 4);
                f32x4 a1 = *reinterpret_cast<const f32x4*>(Xp + abase[mt] + ((ks * 8 + lg * 2 + 1) ^ lr) * 4);
                #pragma unroll
                for (int j = 0; j < 4; ++j) { af[mt][j] = (__bf16)a0[j]; af[mt][4 + j] = (__bf16)a1[j]; }
            }
            #pragma unroll
            for (int ct = 0; ct < 3; ++ct) {
                bf16x8 bf = *reinterpret_cast<const bf16x8*>(
                    Wp + bbase[ct] + (((ks * 4 + lg) ^ (lr & 7)) * 8));
                #pragma unroll
                for (int mt = 0; mt < 2; ++mt)
                    acc[mt][ct] = __builtin_amdgcn_mfma_f32_16x16x32_bf16(af[mt], bf, acc[mt][ct], 0, 0, 0);
            }
        }
        ++sl; if (sl >= 3) sl = 0;
    }

    #pragma unroll
    for (int mt = 0; mt < 2; ++mt) {
        const int rowbase = m0 + wm * 32 + mt * 16 + lg * 4;
        #pragma unroll
        for (int ct = 0; ct < 3; ++ct) {
            const int ntile = wn * 3 + ct;
            const int mtx = ntile >> 2;
            const int d = (ntile & 3) * 16 + lr;
            if (mtx == 0) {
                #pragma unroll
                for (int r = 0; r < 4; ++r)
                    Qb[(size_t)(rowbase + r) * HD + d] = (__bf16)(acc[mt][ct][r] * 0.18033688f);
            } else if (mtx == 1) {
                #pragma unroll
                for (int r = 0; r < 4; ++r)
                    Kb[(size_t)(rowbase + r) * HD + d] = (__bf16)acc[mt][ct][r];
            } else {
                int bb = rowbase >> 11;
                int s0 = rowbase & 2047;
                bf16x4 vv;
                #pragma unroll
                for (int r = 0; r < 4; ++r) vv[r] = (__bf16)acc[mt][ct][r];
                *reinterpret_cast<bf16x4*>(Vt + ((size_t)bb * HD + d) * SEQ + s0) = vv;
            }
        }
    }
}

// ---------------- kernel 2: split-K causal flash attention, 128-row Q tiles,
// 512 thr (8 waves), swapped QK^T, exp2-domain softmax, defer-max, wave skip.
__launch_bounds__(512)
__global__ void k_attn(const __bf16* __restrict__ Qb, const __bf16* __restrict__ Kb,
                       const __bf16* __restrict__ Vt, __bf16* __restrict__ Opart,
                       float* __restrict__ ML, int T, int NC) {
    const int bid = blockIdx.x;
    const int b = bid / (16 * NC);
    const int rem = bid - b * 16 * NC;
    const int qt2 = rem / NC;
    const int c = rem - qt2 * NC;
    const int kmax = 2 * qt2 + 1;             // last causal k-step for this tile
    if (c * T > kmax) return;
    const int kt0 = c * T;
    const int nt = min(T, kmax + 1 - kt0);
    const int q0 = qt2 * 128;

    __shared__ __align__(16) __bf16 Ks[64][72];
    __shared__ __align__(16) __bf16 Vs[64][72];    // [d][key]
    __shared__ __align__(16) __bf16 Ps[128][72];
    const int tid = threadIdx.x;
    const int w = tid >> 6, l = tid & 63;
    const int lr = l & 15, lg = l >> 4;
    const __bf16* Qp = Qb + (size_t)b * SEQ * HD;
    const __bf16* Kp = Kb + (size_t)b * SEQ * HD;
    const __bf16* Vp = Vt + (size_t)b * HD * SEQ;

    const int srow = tid >> 3, sc8 = (tid & 7) * 8;   // 512 units = full 64x64 tile
    const int myq = q0 + 16 * w + lr;

    bf16x8 qa[2];
    #pragma unroll
    for (int ks = 0; ks < 2; ++ks)
        qa[ks] = *reinterpret_cast<const bf16x8*>(
            Qp + (size_t)myq * HD + ks * 32 + lg * 8);

    bf16x8 kpre, vpre;
    {
        const int k0 = kt0 * 64;
        kpre = *reinterpret_cast<const bf16x8*>(Kp + (size_t)(k0 + srow) * HD + sc8);
        vpre = *reinterpret_cast<const bf16x8*>(Vp + (size_t)srow * SEQ + k0 + sc8);
    }

    f32x4 oacc[4];
    #pragma unroll
    for (int r = 0; r < 4; ++r) oacc[r] = f32x4{0.f, 0.f, 0.f, 0.f};
    float m = -1e30f, lsum = 0.f;

    for (int it = 0; it < nt; ++it) {
        const int kt = kt0 + it;
        const int k0 = kt * 64;
        __syncthreads();
        *reinterpret_cast<bf16x8*>(&Ks[srow][sc8]) = kpre;
        *reinterpret_cast<bf16x8*>(&Vs[srow][sc8]) = vpre;
        __syncthreads();
        if (it + 1 < nt) {
            const int k0n = k0 + 64;
            kpre = *reinterpret_cast<const bf16x8*>(Kp + (size_t)(k0n + srow) * HD + sc8);
            vpre = *reinterpret_cast<const bf16x8*>(Vp + (size_t)srow * SEQ + k0n + sc8);
        }

        // wave-level causal skip: all 16 rows of this wave below the key tile
        if (k0 > q0 + 16 * w + 15) continue;

        f32x4 sacc[4];
        #pragma unroll
        for (int t = 0; t < 4; ++t) sacc[t] = f32x4{0.f, 0.f, 0.f, 0.f};
        #pragma unroll
        for (int ks = 0; ks < 2; ++ks) {
            #pragma unroll
            for (int t = 0; t < 4; ++t) {
                bf16x8 kf = *reinterpret_cast<const bf16x8*>(&Ks[16 * t + lr][ks * 32 + lg * 8]);
                sacc[t] = __builtin_amdgcn_mfma_f32_16x16x32_bf16(kf, qa[ks], sacc[t], 0, 0, 0);
            }
        }

        float pmax = -1e30f;
        if (k0 + 63 > q0 + 16 * w) {   // wave-uniform: tile straddles the diagonal
            #pragma unroll
            for (int t = 0; t < 4; ++t)
                #pragma unroll
                for (int r = 0; r < 4; ++r) {
                    float v = sacc[t][r];
                    if ((k0 + 16 * t + lg * 4 + r) > myq) v = -1e30f;
                    sacc[t][r] = v;
                    pmax = fmaxf(pmax, v);
                }
        } else {
            #pragma unroll
            for (int t = 0; t < 4; ++t)
                #pragma unroll
                for (int r = 0; r < 4; ++r) pmax = fmaxf(pmax, sacc[t][r]);
        }
        pmax = fmaxf(pmax, __shfl_xor(pmax, 16));
        pmax = fmaxf(pmax, __shfl_xor(pmax, 32));

        if (!__all(pmax <= m + 12.f)) {      // defer-max: rescale only when needed
            float mnew = fmaxf(m, pmax);
            float fsc = exp2f(m - mnew);
            m = mnew;
            lsum *= fsc;
            #pragma unroll
            for (int r = 0; r < 4; ++r) {
                float fq = __shfl(fsc, (l & 48) + lg * 4 + r);
                #pragma unroll
                for (int t2 = 0; t2 < 4; ++t2) oacc[t2][r] *= fq;
            }
        }

        float rs = 0.f;
        #pragma unroll
        for (int t = 0; t < 4; ++t)
            #pragma unroll
            for (int r = 0; r < 4; ++r) {
                float p = exp2f(sacc[t][r] - m);
                sacc[t][r] = p;
                rs += p;
            }
        rs += __shfl_xor(rs, 16);
        rs += __shfl_xor(rs, 32);
        lsum += rs;

        #pragma unroll
        for (int t = 0; t < 4; ++t) {
            bf16x4 pv;
            #pragma unroll
            for (int r = 0; r < 4; ++r) pv[r] = (__bf16)sacc[t][r];
            *reinterpret_cast<bf16x4*>(&Ps[16 * w + lr][16 * t + lg * 4]) = pv;
        }

        #pragma unroll
        for (int ks = 0; ks < 2; ++ks) {
            bf16x8 pa = *reinterpret_cast<const bf16x8*>(&Ps[16 * w + lr][ks * 32 + lg * 8]);
            #pragma unroll
            for (int t2 = 0; t2 < 4; ++t2) {
                bf16x8 vb = *reinterpret_cast<const bf16x8*>(&Vs[16 * t2 + lr][ks * 32 + lg * 8]);
                oacc[t2] = __builtin_amdgcn_mfma_f32_16x16x32_bf16(pa, vb, oacc[t2], 0, 0, 0);
            }
        }
    }

    const size_t slot = (size_t)bid;
    __bf16* op = Opart + slot * 8192;
    #pragma unroll
    for (int t2 = 0; t2 < 4; ++t2)
        #pragma unroll
        for (int r = 0; r < 4; ++r)
            op[(16 * w + lg * 4 + r) * 64 + 16 * t2 + lr] = (__bf16)oacc[t2][r];
    if (lg == 0) {
        float* ml = ML + slot * 256;
        int row = 16 * w + lr;
        ml[row * 2]     = m;
        ml[row * 2 + 1] = lsum;
    }
}

// ---------------- kernel 3: merge partial chunks -> Out [B][S][64] f32
// 256 blocks x 512 thr: block = (tile 0..127, col-half), thread = (row, 8 cols)
__launch_bounds__(512)
__global__ void k_merge(const __bf16* __restrict__ Opart, const float* __restrict__ ML,
                        float* __restrict__ Out, int T, int NC) {
    const int bq2 = blockIdx.x >> 1;          // b*16 + qt2
    const int half = blockIdx.x & 1;
    const int qt2 = bq2 & 15;
    const int nc = (2 * qt2 + 1) / T + 1;
    const int tid = threadIdx.x;
    const int row = tid >> 2;                 // 0..127
    const int cg = (tid & 3) * 8 + half * 32; // 8 cols
    const int base = bq2 * NC;

    float M = -1e30f;
    for (int c = 0; c < nc; ++c)
        M = fmaxf(M, ML[(size_t)(base + c) * 256 + row * 2]);

    float L = 0.f;
    f32x4 a0{0,0,0,0}, a1{0,0,0,0};
    for (int c = 0; c < nc; ++c) {
        const float* ml = ML + (size_t)(base + c) * 256 + row * 2;
        float wgt = exp2f(ml[0] - M);
        L += ml[1] * wgt;
        bf16x8 v = *reinterpret_cast<const bf16x8*>(
            Opart + (size_t)(base + c) * 8192 + row * 64 + cg);
        #pragma unroll
        for (int j = 0; j < 4; ++j) {
            a0[j] += wgt * (float)v[j];
            a1[j] += wgt * (float)v[4 + j];
        }
    }
    float inv = 1.f / L;
    #pragma unroll
    for (int j = 0; j < 4; ++j) { a0[j] *= inv; a1[j] *= inv; }
    float* o = Out + ((size_t)bq2 * 128 + row) * 64 + cg;
    *reinterpret_cast<f32x4*>(o)     = a0;
    *reinterpret_cast<f32x4*>(o + 4) = a1;
}

extern "C" void kernel_launch(void* const* d_in, const int* in_sizes, int n_in,
                              void* d_out, int out_size, void* d_ws, size_t ws_size,
                              hipStream_t stream) {
    const float* x  = (const float*)d_in[0];
    const float* wq = (const float*)d_in[1];
    const float* wk = (const float*)d_in[2];
    const float* wv = (const float*)d_in[3];
    char* ws = (char*)d_ws;
    __bf16* Wb = (__bf16*)ws;
    __bf16* Qb = (__bf16*)(ws + 524288);
    __bf16* Kb = (__bf16*)(ws + 524288 + 2097152);
    __bf16* Vt = (__bf16*)(ws + 524288 + 2 * 2097152);
    const size_t base = 524288 + 3 * 2097152;
    float* out = (float*)d_out;

    // per-slot: 128 rows ML (1 KB) + 128x64 bf16 partial O (16 KB)
    int NC = (ws_size >= base + (size_t)(8 * 16 * 8) * 17408) ? 8 : 2;
    int T = 32 / NC;
    const int slots = 8 * 16 * NC;
    float*  ML    = (float*)(ws + base);
    __bf16* Opart = (__bf16*)(ws + base + (size_t)slots * 1024);

    hipLaunchKernelGGL(k_convw, dim3(192), dim3(256), 0, stream, wq, wk, wv, Wb);
    hipLaunchKernelGGL(k_proj,  dim3(256), dim3(512), 0, stream, x, Wb, Qb, Kb, Vt);
    hipLaunchKernelGGL(k_attn,  dim3(8 * 16 * NC), dim3(512), 0, stream,
                       Qb, Kb, Vt, Opart, ML, T, NC);
    hipLaunchKernelGGL(k_merge, dim3(256), dim3(512), 0, stream, Opart, ML, out, T, NC);
}